// Round 14
// baseline (204.889 us; speedup 1.0000x reference)
//
#include <hip/hip_runtime.h>
#include <hip/hip_bf16.h>

// Problem constants: B=2, N=2048, E=1024, H=16, D_K=64, GAMMA=1
//   tokens M = 4096, K = 1024
//
// ws layout (ushort elems), SZ = 4096*1024 = 4194304:
//   xbf[SZ] | Wbf[SZ] (Wq,Wk,Wv,Wo @ +0/+1M/+2M/+3M) | Qbf[SZ] | Kbf[SZ]
//   | Vt[SZ] ([bh][64][2048]) | Obf[SZ]
//   | qsqp[64K f32] ksqp[64K f32] maskf[4K] FullVm[2K] den_base[2] kmaxb[32]
//
// Numerics: Qbf holds 2c*q (c = log2 e). qsqp = -c*|q|^2, ksqp = -c*|k|^2.
// z = qsqp + ksqp + 2c*qk = -c*d; sim s = 2^z = exp(-d) in [0,1].
// Softmax weight p = e^s * m  =  m + m*expm1(s).
//   O = FullVm + Sum_slow V*(m*expm1(s));  den = den_base + Sum_slow m*expm1(s)
// Tiles with max z < -14 contribute only their m-part (error < 6e-5/score).
//
// R13: prep_kernel deleted (launch-count cut). maskf/den_base -> cvt_all
// block 0; kmax -> QKV gemm K-epilogue atomicMin; FullVm -> QKV gemm
// V-epilogue (fg-butterfly + 1 atomicAdd per column per wave).

using bf16x8 = __attribute__((ext_vector_type(8))) __bf16;
using f32x4  = __attribute__((ext_vector_type(4))) float;
using f32x16 = __attribute__((ext_vector_type(16))) float;

typedef const __attribute__((address_space(1))) void* gas_t;
typedef __attribute__((address_space(3))) void* las_t;

#define C_LOG2E 1.4426950408889634f
#define TWO_C   2.8853900817779268f
#define NEG_INV_4C (-0.17328679513998632f)

#if __has_builtin(__builtin_amdgcn_exp2f)
#define EXP2(x) __builtin_amdgcn_exp2f(x)
#else
#define EXP2(x) __expf((x) * 0.6931471805599453f)
#endif

static __device__ __forceinline__ unsigned short f2bf(float x) {
  union { float f; unsigned u; } c; c.f = x;
  unsigned u = c.u;
  u += 0x7fffu + ((u >> 16) & 1u);          // round-to-nearest-even
  return (unsigned short)(u >> 16);
}
static __device__ __forceinline__ float bf2f(unsigned short b) {
  union { unsigned u; float f; } c; c.u = ((unsigned)b) << 16;
  return c.f;
}
static __device__ __forceinline__ unsigned cvt_pk_bf16(float lo, float hi) {
  unsigned r;
  asm("v_cvt_pk_bf16_f32 %0, %1, %2" : "=v"(r) : "v"(lo), "v"(hi));
  return r;
}
static __device__ __forceinline__ void permlane32_swap(unsigned &a, unsigned &b) {
#if __has_builtin(__builtin_amdgcn_permlane32_swap)
  auto r = __builtin_amdgcn_permlane32_swap(a, b, false, false);
  a = r[0]; b = r[1];
#else
  asm("v_permlane32_swap_b32 %0, %1" : "+v"(a), "+v"(b));
#endif
}

// counted-vmcnt barrier: wait own oldest loads (leave N newest in flight),
// drain LDS ops, then raw barrier. memory clobber orders all mem ops.
#define SYNC_VM(N)                                                           \
  do {                                                                       \
    asm volatile("s_waitcnt vmcnt(" #N ") lgkmcnt(0)\n\ts_barrier" ::: "memory"); \
    __builtin_amdgcn_sched_barrier(0);                                       \
  } while (0)

// ---------------- fused f32 -> bf16 convert + inits + maskf/den_base ----------------
__global__ __launch_bounds__(256)
void cvt_all(const float* __restrict__ x,  const float* __restrict__ wq,
             const float* __restrict__ wk, const float* __restrict__ wv,
             const float* __restrict__ wo, const int* __restrict__ mask,
             unsigned short* __restrict__ xbf, unsigned short* __restrict__ Wbf,
             float* __restrict__ maskf,
             float* __restrict__ FullVm, float* __restrict__ den_base,
             unsigned* __restrict__ kmax_bits) {
  const int idx = blockIdx.x * 256 + threadIdx.x;
  if (blockIdx.x == 0) {                   // init atomic targets + maskf/den_base
    const int tid = threadIdx.x;
#pragma unroll
    for (int i = 0; i < 8; ++i) FullVm[tid + i * 256] = 0.f;
    if (tid < 32) kmax_bits[tid] = 0xFF800000u;   // -inf bits
    if (tid < 2) den_base[tid] = 0.f;
    __syncthreads();                       // inits visible before atomics below
    float s0 = 0.f, s1 = 0.f;
    for (int i = tid; i < 4096; i += 256) {
      const float mv = (mask[i] == 0) ? 0.f : 1.f;
      maskf[i] = mv;
      if (i < 2048) s0 += mv; else s1 += mv;
    }
#pragma unroll
    for (int off = 32; off >= 1; off >>= 1) {
      s0 += __shfl_xor(s0, off);
      s1 += __shfl_xor(s1, off);
    }
    if ((tid & 63) == 0) {
      atomicAdd(&den_base[0], s0);
      atomicAdd(&den_base[1], s1);
    }
  }
  const float* src; unsigned short* dst; int off;
  if (idx < 1048576) { src = x; dst = xbf; off = idx; }
  else {
    const int r = idx - 1048576;
    const int w = r >> 18;                 // 262144 groups per W
    off = r & 262143;
    src = (w == 0) ? wq : (w == 1) ? wk : (w == 2) ? wv : wo;
    dst = Wbf + (size_t)w * 1048576u;
  }
  const float4 v = ((const float4*)src)[off];
  ushort4 o;
  o.x = f2bf(v.x); o.y = f2bf(v.y); o.z = f2bf(v.z); o.w = f2bf(v.w);
  ((ushort4*)dst)[off] = o;
}

// ---------------- GEMM: C[M][Ncols] = A[M][K] * Bt[Ncols][K]^T ----------------
// 128x128 tile, 4 waves (2x2), BK=32, global_load_lds width 16.
// Counted vmcnt; chunk-XOR swizzle m(r)=(r&3)^((r>>2)&3).
// MODE 0: ring-3, lookahead-2 (3 blocks/CU); epilogue emits Q/K/Vt + qsqp/ksqp
//         + kmax (atomicMin, K-cols) + FullVm (atomicAdd, V-cols).
// MODE 1: ring-4, lookahead-3 (1 block/CU -> LDS free); f32 C out.
template<int MODE>
__global__ __launch_bounds__(256)
void gemm_bt(const unsigned short* __restrict__ A,
             const unsigned short* __restrict__ Bt,
             void* __restrict__ out0, int Kdim,
             float* __restrict__ qsqp, float* __restrict__ ksqp,
             const float* __restrict__ maskf,
             float* __restrict__ FullVm,
             unsigned* __restrict__ kmax_bits) {
  constexpr int RING = (MODE == 0) ? 3 : 4;
  __shared__ unsigned short As[RING][4096];   // [buf][128][32] chunk-swizzled
  __shared__ unsigned short Bs[RING][4096];
  const int t  = threadIdx.x;
  const int m0 = blockIdx.x * 128;
  const int n0 = blockIdx.y * 128;
  const int srow = t >> 2;
  const int scol = (((t & 3) ^ (srow & 3) ^ ((srow >> 2) & 3))) * 8;
  const unsigned short* pA = A  + (size_t)(m0 + srow) * Kdim + scol;
  const unsigned short* pB = Bt + (size_t)(n0 + srow) * Kdim + scol;
  const size_t rowskip = (size_t)64 * Kdim;

  const int wave = t >> 6, lane = t & 63;
  const int wm = (wave >> 1) * 64, wn = (wave & 1) * 64;
  const int fr = lane & 15, fg = lane >> 4;
  const int fswz = fg ^ (fr & 3) ^ ((fr >> 2) & 3);
  const int aoff = (wm + fr) * 32 + fswz * 8;
  const int boff = (wn + fr) * 32 + fswz * 8;

  f32x4 acc[4][4];
#pragma unroll
  for (int mi = 0; mi < 4; ++mi)
#pragma unroll
    for (int ni = 0; ni < 4; ++ni)
      acc[mi][ni] = (f32x4){0.f, 0.f, 0.f, 0.f};

#define GSTAGE(bi, kk)                                                                                  \
  do {                                                                                                  \
    const int kc = (kk) * 32;                                                                           \
    __builtin_amdgcn_global_load_lds((gas_t)(const void*)(pA + kc),           (las_t)(void*)(As[bi] + t * 8),        16, 0, 0); \
    __builtin_amdgcn_global_load_lds((gas_t)(const void*)(pA + kc + rowskip), (las_t)(void*)(As[bi] + 2048 + t * 8), 16, 0, 0); \
    __builtin_amdgcn_global_load_lds((gas_t)(const void*)(pB + kc),           (las_t)(void*)(Bs[bi] + t * 8),        16, 0, 0); \
    __builtin_amdgcn_global_load_lds((gas_t)(const void*)(pB + kc + rowskip), (las_t)(void*)(Bs[bi] + 2048 + t * 8), 16, 0, 0); \
  } while (0)

  const int NK = Kdim >> 5;
  if constexpr (MODE == 0) {
    GSTAGE(0, 0);
    GSTAGE(1, 1);
    for (int ks = 0; ks < NK; ++ks) {
      const int cur = ks % 3;
      if (ks + 1 < NK) SYNC_VM(4); else SYNC_VM(0);
      if (ks + 2 < NK) GSTAGE((ks + 2) % 3, ks + 2);

      bf16x8 af[4], bfr[4];
#pragma unroll
      for (int mi = 0; mi < 4; ++mi) af[mi]  = *(const bf16x8*)(As[cur] + aoff + mi * 512);
#pragma unroll
      for (int ni = 0; ni < 4; ++ni) bfr[ni] = *(const bf16x8*)(Bs[cur] + boff + ni * 512);
#pragma unroll
      for (int mi = 0; mi < 4; ++mi)
#pragma unroll
        for (int ni = 0; ni < 4; ++ni)
          acc[mi][ni] = __builtin_amdgcn_mfma_f32_16x16x32_bf16(af[mi], bfr[ni], acc[mi][ni], 0, 0, 0);
    }
  } else {
    GSTAGE(0, 0);
    GSTAGE(1, 1);
    GSTAGE(2, 2);
    for (int ks = 0; ks < NK; ++ks) {
      const int cur = ks & 3;
      if (ks + 2 < NK) SYNC_VM(8);
      else if (ks + 1 < NK) SYNC_VM(4);
      else SYNC_VM(0);
      if (ks + 3 < NK) GSTAGE((ks + 3) & 3, ks + 3);   // buf (ks-1)%4: post-barrier safe

      bf16x8 af[4], bfr[4];
#pragma unroll
      for (int mi = 0; mi < 4; ++mi) af[mi]  = *(const bf16x8*)(As[cur] + aoff + mi * 512);
#pragma unroll
      for (int ni = 0; ni < 4; ++ni) bfr[ni] = *(const bf16x8*)(Bs[cur] + boff + ni * 512);
#pragma unroll
      for (int mi = 0; mi < 4; ++mi)
#pragma unroll
        for (int ni = 0; ni < 4; ++ni)
          acc[mi][ni] = __builtin_amdgcn_mfma_f32_16x16x32_bf16(af[mi], bfr[ni], acc[mi][ni], 0, 0, 0);
    }
  }
#undef GSTAGE

  // epilogue: C/D layout col = lane&15, row = (lane>>4)*4 + r  [m89-verified]
  if constexpr (MODE == 1) {                           // f32 out
    float* dst = (float*)out0;
#pragma unroll
    for (int mi = 0; mi < 4; ++mi) {
      const int gm = m0 + wm + mi * 16 + fg * 4;
#pragma unroll
      for (int ni = 0; ni < 4; ++ni) {
        const int gn = n0 + wn + ni * 16 + fr;
#pragma unroll
        for (int r = 0; r < 4; ++r)
          dst[(size_t)(gm + r) * 1024 + gn] = acc[mi][ni][r];
      }
    }
    return;
  } else {
    const int wavecol = n0 + wn;                       // wave-uniform
    const int zz = wavecol >> 10;
    unsigned short* outw = (unsigned short*)out0;
    if (zz < 2) {                                      // Q (scaled by 2c) or K
      const float sc = (zz == 0) ? TWO_C : 1.0f;
      const float qscale = (zz == 0) ? NEG_INV_4C : -C_LOG2E;
      unsigned short* dst = outw + (size_t)zz * 4194304u;
      const int hh = (wavecol & 1023) >> 6;            // head (64-col span = 1 head)
      float* dq = (zz == 0) ? qsqp : ksqp;
#pragma unroll
      for (int mi = 0; mi < 4; ++mi) {
        const int gm = m0 + wm + mi * 16 + fg * 4;
        float s0 = 0.f, s1 = 0.f, s2 = 0.f, s3 = 0.f;
#pragma unroll
        for (int ni = 0; ni < 4; ++ni) {
          const int col = (wavecol + ni * 16 + fr) & 1023;
          const unsigned short u0 = f2bf(acc[mi][ni][0] * sc);
          const unsigned short u1 = f2bf(acc[mi][ni][1] * sc);
          const unsigned short u2 = f2bf(acc[mi][ni][2] * sc);
          const unsigned short u3 = f2bf(acc[mi][ni][3] * sc);
          dst[(size_t)(gm + 0) * 1024 + col] = u0;
          dst[(size_t)(gm + 1) * 1024 + col] = u1;
          dst[(size_t)(gm + 2) * 1024 + col] = u2;
          dst[(size_t)(gm + 3) * 1024 + col] = u3;
          const float r0 = bf2f(u0), r1 = bf2f(u1), r2 = bf2f(u2), r3 = bf2f(u3);
          s0 += r0 * r0; s1 += r1 * r1; s2 += r2 * r2; s3 += r3 * r3;
        }
#pragma unroll
        for (int off2 = 1; off2 < 16; off2 <<= 1) {    // reduce over fr lanes
          s0 += __shfl_xor(s0, off2);
          s1 += __shfl_xor(s1, off2);
          s2 += __shfl_xor(s2, off2);
          s3 += __shfl_xor(s3, off2);
        }
        if (fr == 0) {
          const int bb = gm >> 11;
          float4 o4;
          o4.x = s0 * qscale; o4.y = s1 * qscale;
          o4.z = s2 * qscale; o4.w = s3 * qscale;
          *(float4*)(dq + (bb * 16 + hh) * 2048 + (gm & 2047)) = o4;
          if (zz == 1) {                               // kmax (vals<=0: fmax==umin)
            const float mx = fmaxf(fmaxf(o4.x, o4.y), fmaxf(o4.z, o4.w));
            atomicMin(kmax_bits + (bb * 16 + hh), __float_as_uint(mx));
          }
        }
      }
    } else {                                           // V -> Vt[bh][d][n] + FullVm
      const int bb = (m0 + wm) >> 11;                  // uniform (2048%128==0)
      const int hh = (wavecol & 1023) >> 6;
      float fvp[4] = {0.f, 0.f, 0.f, 0.f};             // per-ni column partials
#pragma unroll
      for (int mi = 0; mi < 4; ++mi) {
        const int gm = m0 + wm + mi * 16 + fg * 4;
        const int nn = gm & 2047;
        const float4 mv = *(const float4*)(maskf + bb * 2048 + nn);
#pragma unroll
        for (int ni = 0; ni < 4; ++ni) {
          const int gn = n0 + wn + ni * 16 + fr;
          const int col = gn & 1023;
          ushort4 o4;
          o4.x = f2bf(acc[mi][ni][0]); o4.y = f2bf(acc[mi][ni][1]);
          o4.z = f2bf(acc[mi][ni][2]); o4.w = f2bf(acc[mi][ni][3]);
          const int dd = col & 63;
          unsigned short* vt = outw + (size_t)2 * 4194304u;
          *(ushort4*)(vt + ((size_t)((bb * 16 + hh) * 64 + dd)) * 2048 + nn) = o4;
          fvp[ni] += mv.x * bf2f(o4.x) + mv.y * bf2f(o4.y) +
                     mv.z * bf2f(o4.z) + mv.w * bf2f(o4.w);
        }
      }
      // butterfly over fg groups (lane = fg*16+fr): xor16 + xor32 sums 4 fg
#pragma unroll
      for (int ni = 0; ni < 4; ++ni) {
        fvp[ni] += __shfl_xor(fvp[ni], 16);
        fvp[ni] += __shfl_xor(fvp[ni], 32);
      }
      if (fg == 0) {                                   // lane = fr
#pragma unroll
        for (int ni = 0; ni < 4; ++ni)
          atomicAdd(&FullVm[(bb * 16 + hh) * 64 + ni * 16 + fr], fvp[ni]);
      }
    }
  }
}

// ---------------- fused RBF attention, classify-and-skip (2-wave blocks) ----------------
// grid (32 bh, 32 qtiles), 2 waves; wave = q-group (32 rows), full 64-k tile
// per wave as two sequential 32-k sets (st regs reused). Ring-4 + vmcnt(8):
// two K-tiles in flight. den complete per wave -> no end-combine.
__global__ __launch_bounds__(128)
void attn_kernel(const unsigned short* __restrict__ Qbf,
                 const unsigned short* __restrict__ Kbf,
                 const unsigned short* __restrict__ Vt,
                 const float* __restrict__ qsqp,
                 const float* __restrict__ ksqp,
                 const float* __restrict__ maskf,
                 const float* __restrict__ FullVm,
                 const float* __restrict__ den_base,
                 const float* __restrict__ kmaxb,
                 unsigned short* __restrict__ Obf) {
  __shared__ unsigned short Ks[4][4096];   // [buf][64 k][64 d] swizzled (chunk^=row&7)

  const int bh = blockIdx.x;
  const int b = bh >> 4, h = bh & 15;
  const int t = threadIdx.x;
  const int wave = t >> 6, lane = t & 63;
  const int li = lane & 31, hi = lane >> 5;
  const int q0 = blockIdx.y * 64 + wave * 32;
  const int qrow = q0 + li;

  // Q fragments: B-operand, lane holds Q[qrow][dblk*16 + hi*8 + e]
  const unsigned short* Qr = Qbf + (size_t)(b * 2048 + qrow) * 1024 + h * 64 + hi * 8;
  bf16x8 qf[4];
#pragma unroll
  for (int dblk = 0; dblk < 4; ++dblk) qf[dblk] = *(const bf16x8*)(Qr + dblk * 16);

  const float qsl = qsqp[bh * 2048 + qrow];
  const float thr = -14.0f - qsl - kmaxb[bh];   // st_raw > thr possible => slow path

  const unsigned short* Kbase = Kbf + (size_t)b * 2048 * 1024 + h * 64;
  const unsigned short* VtB = Vt + (size_t)bh * 64 * 2048;

  // staging: 8KB tile = 512 x 16B chunks; 128 threads own 4 chunks each.
  // row = p>>3, slot cp = p&7 holds logical chunk cl = cp ^ (row&7).
  const int p0 = t,        r0 = p0 >> 3, c0 = (p0 & 7) ^ (r0 & 7);
  const int p1 = 128 + t,  r1 = p1 >> 3, c1 = (p1 & 7) ^ (r1 & 7);
  const int p2 = 256 + t,  r2 = p2 >> 3, c2 = (p2 & 7) ^ (r2 & 7);
  const int p3 = 384 + t,  r3 = p3 >> 3, c3 = (p3 & 7) ^ (r3 & 7);

  f32x16 oa0, oa1;
#pragma unroll
  for (int r = 0; r < 16; ++r) { oa0[r] = 0.f; oa1[r] = 0.f; }
  float den = 0.f;

#define STAGE(bi, tj)                                                                               \
  do {                                                                                              \
    const int j0s = (tj) * 64;                                                                      \
    __builtin_amdgcn_global_load_lds((gas_t)(const void*)(Kbase + (size_t)(j0s + r0) * 1024 + c0 * 8), \
                                     (las_t)(void*)(Ks[bi] + p0 * 8), 16, 0, 0);                    \
    __builtin_amdgcn_global_load_lds((gas_t)(const void*)(Kbase + (size_t)(j0s + r1) * 1024 + c1 * 8), \
                                     (las_t)(void*)(Ks[bi] + p1 * 8), 16, 0, 0);                    \
    __builtin_amdgcn_global_load_lds((gas_t)(const void*)(Kbase + (size_t)(j0s + r2) * 1024 + c2 * 8), \
                                     (las_t)(void*)(Ks[bi] + p2 * 8), 16, 0, 0);                    \
    __builtin_amdgcn_global_load_lds((gas_t)(const void*)(Kbase + (size_t)(j0s + r3) * 1024 + c3 * 8), \
                                     (las_t)(void*)(Ks[bi] + p3 * 8), 16, 0, 0);                    \
  } while (0)

  STAGE(0, 0);
  STAGE(1, 1);
  STAGE(2, 2);

  const int ksw = li & 7;            // K LDS row = s*32+li; s*32 ≡ 0 (mod 8)

  for (int tj = 0; tj < 32; ++tj) {
    const int cur = tj & 3;
    if (tj + 2 < 32) SYNC_VM(8);
    else if (tj + 1 < 32) SYNC_VM(4);
    else SYNC_VM(0);
    if (tj + 3 < 32) STAGE((tj + 3) & 3, tj + 3);

#pragma unroll
    for (int s = 0; s < 2; ++s) {    // two 32-k sets of the 64-k tile
      // QK^T raw: st = K_rows(s*32..s*32+31) * Q^T (C-init 0)
      const unsigned short* Krow = Ks[cur] + (s * 32 + li) * 64;
      f32x16 st;
#pragma unroll
      for (int r = 0; r < 16; ++r) st[r] = 0.f;
#pragma unroll
      for (int dblk = 0; dblk < 4; ++dblk) {
        const bf16x8 kf = *(const bf16x8*)(Krow + ((dblk * 2 + hi) ^ ksw) * 8);
        st = __builtin_amdgcn_mfma_f32_32x32x16_bf16(kf, qf[dblk], st, 0, 0, 0);
      }

      // max tree
      const float a0 = fmaxf(fmaxf(st[0], st[1]), st[2]);
      const float a1 = fmaxf(fmaxf(st[3], st[4]), st[5]);
      const float a2 = fmaxf(fmaxf(st[6], st[7]), st[8]);
      const float a3 = fmaxf(fmaxf(st[9], st[10]), st[11]);
      const float a4 = fmaxf(fmaxf(st[12], st[13]), st[14]);
      const float a5 = fmaxf(fmaxf(a0, a1), st[15]);
      const float a6 = fmaxf(fmaxf(a2, a3), a4);
      const float lmax = fmaxf(a5, a6);

      if (__any(lmax > thr)) {
        // ---- slow path (rare): ds = m * expm1(2^z), z = st + qsl + ksq' ----
        const int j0 = tj * 64 + s * 32;
        const float* ksb2 = ksqp + bh * 2048 + j0 + 4 * hi;
        const float* mfb2 = maskf + b * 2048 + j0 + 4 * hi;
        const float4 kq0 = *(const float4*)(ksb2);
        const float4 kq1 = *(const float4*)(ksb2 + 8);
        const float4 kq2 = *(const float4*)(ksb2 + 16);
        const float4 kq3 = *(const float4*)(ksb2 + 24);
        const float4 mf0 = *(const float4*)(mfb2);
        const float4 mf1 = *(const float4*)(mfb2 + 8);
        const float4 mf2 = *(const float4*)(mfb2 + 16);
        const float4 mf3 = *(const float4*)(mfb2 + 24);
        const float kqa[16] = {kq0.x, kq0.y, kq0.z, kq0.w, kq1.x, kq1.y, kq1.z, kq1.w,
                               kq2.x, kq2.y, kq2.z, kq2.w, kq3.x, kq3.y, kq3.z, kq3.w};
        const float mfa[16] = {mf0.x, mf0.y, mf0.z, mf0.w, mf1.x, mf1.y, mf1.z, mf1.w,
                               mf2.x, mf2.y, mf2.z, mf2.w, mf3.x, mf3.y, mf3.z, mf3.w};
        float dsv[16];
#pragma unroll
        for (int r = 0; r < 16; ++r) {
          const float z = __builtin_fminf(st[r] + qsl + kqa[r], 0.f);
          const float sx = EXP2(z);
          // expm1(s)/s = 1 + s/2 + s^2/6 + s^3/24 + s^4/120
          float pl = __builtin_fmaf(sx, 1.f / 120.f, 1.f / 24.f);
          pl = __builtin_fmaf(sx, pl, 1.f / 6.f);
          pl = __builtin_fmaf(sx, pl, 0.5f);
          pl = __builtin_fmaf(sx, pl, 1.f);
          const float d_ = sx * pl * mfa[r];
          dsv[r] = d_;
          den += d_;
        }

        // P redistribution: cvt_pk pairs, permlane32_swap -> B-fragments
        unsigned u00 = cvt_pk_bf16(dsv[0],  dsv[1]);
        unsigned u01 = cvt_pk_bf16(dsv[2],  dsv[3]);
        unsigned u10 = cvt_pk_bf16(dsv[4],  dsv[5]);
        unsigned u11 = cvt_pk_bf16(dsv[6],  dsv[7]);
        unsigned u20 = cvt_pk_bf16(dsv[8],  dsv[9]);
        unsigned u21 = cvt_pk_bf16(dsv[10], dsv[11]);
        unsigned u30 = cvt_pk_bf16(dsv[12], dsv[13]);
        unsigned u31 = cvt_pk_bf16(dsv[14], dsv[15]);
        permlane32_swap(u00, u10);
        permlane32_swap(u01, u11);
        permlane32_swap(u20, u30);
        permlane32_swap(u21, u31);
        union { unsigned u[4]; bf16x8 v; } pf0, pf1;
        pf0.u[0] = u00; pf0.u[1] = u01; pf0.u[2] = u10; pf0.u[3] = u11;
        pf1.u[0] = u20; pf1.u[1] = u21; pf1.u[2] = u30; pf1.u[3] = u31;

        // PV: O^T[d][q] += V^T[d][k] * dP[k][q];  V direct from global (L2-hit)
#pragma unroll
        for (int dh = 0; dh < 2; ++dh) {
          const unsigned short* Vrow = VtB + (size_t)(dh * 32 + li) * 2048 + j0;
          const bf16x8 vf0 = *(const bf16x8*)(Vrow + hi * 8);
          const bf16x8 vf1 = *(const bf16x8*)(Vrow + 16 + hi * 8);
          if (dh == 0) {
            oa0 = __builtin_amdgcn_mfma_f32_32x32x16_bf16(vf0, pf0.v, oa0, 0, 0, 0);
            oa0 = __builtin_amdgcn_mfma_f32_32x32x16_bf16(vf1, pf1.v, oa0, 0, 0, 0);
          } else {
            oa1 = __builtin_amdgcn_mfma_f32_32x32x16_bf16(vf0, pf0.v, oa1, 0, 0, 0);
            oa1 = __builtin_amdgcn_mfma_f32_32x32x16_bf16(vf1, pf1.v, oa1, 0, 0, 0);
          }
        }
      }
    }
  }
#undef STAGE

  // den over hi halves (within wave); complete per wave (wave saw all k)
  den += __shfl_xor(den, 32);
  const float inv = 1.f / (den_base[b] + den);
  const float* fvm = FullVm + bh * 64;
  unsigned short* orow = Obf + (size_t)(b * 2048 + qrow) * 1024 + h * 64;
#pragma unroll
  for (int dh = 0; dh < 2; ++dh)
#pragma unroll
    for (int w = 0; w < 4; ++w) {
      float v0, v1, v2, v3;
      if (dh == 0) {
        v0 = oa0[4 * w];     v1 = oa0[4 * w + 1];
        v2 = oa0[4 * w + 2]; v3 = oa0[4 * w + 3];
      } else {
        v0 = oa1[4 * w];     v1 = oa1[4 * w + 1];
        v2 = oa1[4 * w + 2]; v3 = oa1[4 * w + 3];
      }
      // d = 32*dh + 8*w + 4*hi + i
      const float4 fv = *(const float4*)(fvm + dh * 32 + w * 8 + hi * 4);
      ushort4 o4;
      o4.x = f2bf((v0 + fv.x) * inv);
      o4.y = f2bf((v1 + fv.y) * inv);
      o4.z = f2bf((v2 + fv.z) * inv);
      o4.w = f2bf((v3 + fv.w) * inv);
      *(ushort4*)(orow + dh * 32 + w * 8 + hi * 4) = o4;
    }
}

extern "C" void kernel_launch(void* const* d_in, const int* in_sizes, int n_in,
                              void* d_out, int out_size, void* d_ws, size_t ws_size,
                              hipStream_t stream) {
  const float* x  = (const float*)d_in[0];
  const float* Wq = (const float*)d_in[1];
  const float* Wk = (const float*)d_in[2];
  const float* Wv = (const float*)d_in[3];
  const float* Wo = (const float*)d_in[4];
  const int* mask = (const int*)d_in[5];

  unsigned short* ws = (unsigned short*)d_ws;
  const size_t SZ = 4194304;                 // 4096*1024
  unsigned short* xbf = ws;
  unsigned short* Wbf = ws + SZ;             // Wq,Wk,Wv,Wo @ +0/+1M/+2M/+3M
  unsigned short* Qbf = ws + 2 * SZ;
  unsigned short* Kbf = ws + 3 * SZ;         // must be Qbf + SZ (gemm mode 0 relies on it)
  unsigned short* Vt  = ws + 4 * SZ;         // [bh][64][2048]
  unsigned short* Obf = ws + 5 * SZ;
  float* qsqp = (float*)(ws + 6 * SZ);
  float* ksqp = qsqp + 65536;
  float* maskf = ksqp + 65536;
  float* FullVm = maskf + 4096;
  float* den_base = FullVm + 2048;
  float* kmaxb = den_base + 2;               // also used as unsigned bits

  // 1) f32 -> bf16 + inits + maskf/den_base (single fused launch)
  cvt_all<<<8192, 256, 0, stream>>>(x, Wq, Wk, Wv, Wo, mask, xbf, Wbf,
                                    maskf, FullVm, den_base, (unsigned*)kmaxb);

  // 2) fused QKV projection: x @ [Wq;Wk;Wv]^T
  //    (Q prescaled; emits qsqp/ksqp + kmax + FullVm)
  gemm_bt<0><<<dim3(32, 24), 256, 0, stream>>>(xbf, Wbf, Qbf, 1024, qsqp, ksqp,
                                               maskf, FullVm, (unsigned*)kmaxb);

  // 3) fused RBF attention -> Obf
  attn_kernel<<<dim3(32, 32), 128, 0, stream>>>(Qbf, Kbf, Vt, qsqp, ksqp, maskf,
                                                FullVm, den_base, kmaxb, Obf);

  // 4) output projection: Obf @ Wo^T -> f32 d_out (deep-pipelined: 1 block/CU)
  gemm_bt<1><<<dim3(32, 8), 256, 0, stream>>>(Obf, Wbf + 3145728, d_out, 1024,
                                              nullptr, nullptr, nullptr, nullptr,
                                              nullptr);
}

// Round 15
// 108.427 us; speedup vs baseline: 1.8896x; 1.8896x over previous
//
#include <hip/hip_runtime.h>
#include <hip/hip_bf16.h>

// Problem constants: B=2, N=2048, E=1024, H=16, D_K=64, GAMMA=1
//   tokens M = 4096, K = 1024
//
// ws layout (ushort elems), SZ = 4096*1024 = 4194304:
//   xbf[SZ] | Wbf[SZ] (Wq,Wk,Wv,Wo @ +0/+1M/+2M/+3M) | Qbf[SZ] | Kbf[SZ]
//   | Vt[SZ] ([bh][64][2048]) | Obf[SZ]
//   | qsqp[64K f32] ksqp[64K f32] maskf[4K] FullVm[2K] den_base[2] kmaxb[32]
//
// Numerics: Qbf holds 2c*q (c = log2 e). qsqp = -c*|q|^2, ksqp = -c*|k|^2.
// z = qsqp + ksqp + 2c*qk = -c*d; sim s = 2^z = exp(-d) in [0,1].
// Softmax weight p = e^s * m  =  m + m*expm1(s).
//   O = FullVm + Sum_slow V*(m*expm1(s));  den = den_base + Sum_slow m*expm1(s)
// Tiles with max z < -14 contribute only their m-part (error < 6e-5/score).
//
// R14: exact revert to the R12 best-known state (108.6 us). R13's epilogue
// fusion (kmax/FullVm into gemm) regressed BOTH template instantiations to
// 146 us (rule #19 codegen coupling + heavier epilogue re-scheduling the
// K-loop) -> reverted; prep_kernel restored.

using bf16x8 = __attribute__((ext_vector_type(8))) __bf16;
using f32x4  = __attribute__((ext_vector_type(4))) float;
using f32x16 = __attribute__((ext_vector_type(16))) float;

typedef const __attribute__((address_space(1))) void* gas_t;
typedef __attribute__((address_space(3))) void* las_t;

#define C_LOG2E 1.4426950408889634f
#define TWO_C   2.8853900817779268f
#define NEG_INV_4C (-0.17328679513998632f)

#if __has_builtin(__builtin_amdgcn_exp2f)
#define EXP2(x) __builtin_amdgcn_exp2f(x)
#else
#define EXP2(x) __expf((x) * 0.6931471805599453f)
#endif

static __device__ __forceinline__ unsigned short f2bf(float x) {
  union { float f; unsigned u; } c; c.f = x;
  unsigned u = c.u;
  u += 0x7fffu + ((u >> 16) & 1u);          // round-to-nearest-even
  return (unsigned short)(u >> 16);
}
static __device__ __forceinline__ float bf2f(unsigned short b) {
  union { unsigned u; float f; } c; c.u = ((unsigned)b) << 16;
  return c.f;
}
static __device__ __forceinline__ unsigned cvt_pk_bf16(float lo, float hi) {
  unsigned r;
  asm("v_cvt_pk_bf16_f32 %0, %1, %2" : "=v"(r) : "v"(lo), "v"(hi));
  return r;
}
static __device__ __forceinline__ void permlane32_swap(unsigned &a, unsigned &b) {
#if __has_builtin(__builtin_amdgcn_permlane32_swap)
  auto r = __builtin_amdgcn_permlane32_swap(a, b, false, false);
  a = r[0]; b = r[1];
#else
  asm("v_permlane32_swap_b32 %0, %1" : "+v"(a), "+v"(b));
#endif
}

// counted-vmcnt barrier: wait own oldest loads (leave N newest in flight),
// drain LDS ops, then raw barrier. memory clobber orders all mem ops.
#define SYNC_VM(N)                                                           \
  do {                                                                       \
    asm volatile("s_waitcnt vmcnt(" #N ") lgkmcnt(0)\n\ts_barrier" ::: "memory"); \
    __builtin_amdgcn_sched_barrier(0);                                       \
  } while (0)

// ---------------- fused f32 -> bf16 convert + accumulator inits ----------------
__global__ __launch_bounds__(256)
void cvt_all(const float* __restrict__ x,  const float* __restrict__ wq,
             const float* __restrict__ wk, const float* __restrict__ wv,
             const float* __restrict__ wo,
             unsigned short* __restrict__ xbf, unsigned short* __restrict__ Wbf,
             float* __restrict__ FullVm, float* __restrict__ den_base,
             unsigned* __restrict__ kmax_bits) {
  const int idx = blockIdx.x * 256 + threadIdx.x;
  if (blockIdx.x == 0) {                   // init atomic targets (pre-gemm)
    const int tid = threadIdx.x;
#pragma unroll
    for (int i = 0; i < 8; ++i) FullVm[tid + i * 256] = 0.f;
    if (tid < 32) kmax_bits[tid] = 0xFF800000u;   // -inf bits
    if (tid < 2) den_base[tid] = 0.f;
  }
  const float* src; unsigned short* dst; int off;
  if (idx < 1048576) { src = x; dst = xbf; off = idx; }
  else {
    const int r = idx - 1048576;
    const int w = r >> 18;                 // 262144 groups per W
    off = r & 262143;
    src = (w == 0) ? wq : (w == 1) ? wk : (w == 2) ? wv : wo;
    dst = Wbf + (size_t)w * 1048576u;
  }
  const float4 v = ((const float4*)src)[off];
  ushort4 o;
  o.x = f2bf(v.x); o.y = f2bf(v.y); o.z = f2bf(v.z); o.w = f2bf(v.w);
  ((ushort4*)dst)[off] = o;
}

// ---------------- GEMM: C[M][Ncols] = A[M][K] * Bt[Ncols][K]^T ----------------
// 128x128 tile, 4 waves (2x2), BK=32, global_load_lds width 16.
// Counted vmcnt; chunk-XOR swizzle m(r)=(r&3)^((r>>2)&3).
// MODE 0: ring-3, lookahead-2 (3 blocks/CU); epilogue emits Q/K/Vt + qsqp/ksqp.
// MODE 1: ring-4, lookahead-3 (1 block/CU -> LDS free); f32 C out.
template<int MODE>
__global__ __launch_bounds__(256)
void gemm_bt(const unsigned short* __restrict__ A,
             const unsigned short* __restrict__ Bt,
             void* __restrict__ out0, int Kdim,
             float* __restrict__ qsqp, float* __restrict__ ksqp) {
  constexpr int RING = (MODE == 0) ? 3 : 4;
  __shared__ unsigned short As[RING][4096];   // [buf][128][32] chunk-swizzled
  __shared__ unsigned short Bs[RING][4096];
  const int t  = threadIdx.x;
  const int m0 = blockIdx.x * 128;
  const int n0 = blockIdx.y * 128;
  const int srow = t >> 2;
  const int scol = (((t & 3) ^ (srow & 3) ^ ((srow >> 2) & 3))) * 8;
  const unsigned short* pA = A  + (size_t)(m0 + srow) * Kdim + scol;
  const unsigned short* pB = Bt + (size_t)(n0 + srow) * Kdim + scol;
  const size_t rowskip = (size_t)64 * Kdim;

  const int wave = t >> 6, lane = t & 63;
  const int wm = (wave >> 1) * 64, wn = (wave & 1) * 64;
  const int fr = lane & 15, fg = lane >> 4;
  const int fswz = fg ^ (fr & 3) ^ ((fr >> 2) & 3);
  const int aoff = (wm + fr) * 32 + fswz * 8;
  const int boff = (wn + fr) * 32 + fswz * 8;

  f32x4 acc[4][4];
#pragma unroll
  for (int mi = 0; mi < 4; ++mi)
#pragma unroll
    for (int ni = 0; ni < 4; ++ni)
      acc[mi][ni] = (f32x4){0.f, 0.f, 0.f, 0.f};

#define GSTAGE(bi, kk)                                                                                  \
  do {                                                                                                  \
    const int kc = (kk) * 32;                                                                           \
    __builtin_amdgcn_global_load_lds((gas_t)(const void*)(pA + kc),           (las_t)(void*)(As[bi] + t * 8),        16, 0, 0); \
    __builtin_amdgcn_global_load_lds((gas_t)(const void*)(pA + kc + rowskip), (las_t)(void*)(As[bi] + 2048 + t * 8), 16, 0, 0); \
    __builtin_amdgcn_global_load_lds((gas_t)(const void*)(pB + kc),           (las_t)(void*)(Bs[bi] + t * 8),        16, 0, 0); \
    __builtin_amdgcn_global_load_lds((gas_t)(const void*)(pB + kc + rowskip), (las_t)(void*)(Bs[bi] + 2048 + t * 8), 16, 0, 0); \
  } while (0)

  const int NK = Kdim >> 5;
  if constexpr (MODE == 0) {
    GSTAGE(0, 0);
    GSTAGE(1, 1);
    for (int ks = 0; ks < NK; ++ks) {
      const int cur = ks % 3;
      if (ks + 1 < NK) SYNC_VM(4); else SYNC_VM(0);
      if (ks + 2 < NK) GSTAGE((ks + 2) % 3, ks + 2);

      bf16x8 af[4], bfr[4];
#pragma unroll
      for (int mi = 0; mi < 4; ++mi) af[mi]  = *(const bf16x8*)(As[cur] + aoff + mi * 512);
#pragma unroll
      for (int ni = 0; ni < 4; ++ni) bfr[ni] = *(const bf16x8*)(Bs[cur] + boff + ni * 512);
#pragma unroll
      for (int mi = 0; mi < 4; ++mi)
#pragma unroll
        for (int ni = 0; ni < 4; ++ni)
          acc[mi][ni] = __builtin_amdgcn_mfma_f32_16x16x32_bf16(af[mi], bfr[ni], acc[mi][ni], 0, 0, 0);
    }
  } else {
    GSTAGE(0, 0);
    GSTAGE(1, 1);
    GSTAGE(2, 2);
    for (int ks = 0; ks < NK; ++ks) {
      const int cur = ks & 3;
      if (ks + 2 < NK) SYNC_VM(8);
      else if (ks + 1 < NK) SYNC_VM(4);
      else SYNC_VM(0);
      if (ks + 3 < NK) GSTAGE((ks + 3) & 3, ks + 3);   // buf (ks-1)%4: post-barrier safe

      bf16x8 af[4], bfr[4];
#pragma unroll
      for (int mi = 0; mi < 4; ++mi) af[mi]  = *(const bf16x8*)(As[cur] + aoff + mi * 512);
#pragma unroll
      for (int ni = 0; ni < 4; ++ni) bfr[ni] = *(const bf16x8*)(Bs[cur] + boff + ni * 512);
#pragma unroll
      for (int mi = 0; mi < 4; ++mi)
#pragma unroll
        for (int ni = 0; ni < 4; ++ni)
          acc[mi][ni] = __builtin_amdgcn_mfma_f32_16x16x32_bf16(af[mi], bfr[ni], acc[mi][ni], 0, 0, 0);
    }
  }
#undef GSTAGE

  // epilogue: C/D layout col = lane&15, row = (lane>>4)*4 + r  [m89-verified]
  if constexpr (MODE == 1) {                           // f32 out
    float* dst = (float*)out0;
#pragma unroll
    for (int mi = 0; mi < 4; ++mi) {
      const int gm = m0 + wm + mi * 16 + fg * 4;
#pragma unroll
      for (int ni = 0; ni < 4; ++ni) {
        const int gn = n0 + wn + ni * 16 + fr;
#pragma unroll
        for (int r = 0; r < 4; ++r)
          dst[(size_t)(gm + r) * 1024 + gn] = acc[mi][ni][r];
      }
    }
    return;
  } else {
    const int wavecol = n0 + wn;                       // wave-uniform
    const int zz = wavecol >> 10;
    unsigned short* outw = (unsigned short*)out0;
    if (zz < 2) {                                      // Q (scaled by 2c) or K
      const float sc = (zz == 0) ? TWO_C : 1.0f;
      const float qscale = (zz == 0) ? NEG_INV_4C : -C_LOG2E;
      unsigned short* dst = outw + (size_t)zz * 4194304u;
      const int hh = (wavecol & 1023) >> 6;            // head (64-col span = 1 head)
      float* dq = (zz == 0) ? qsqp : ksqp;
#pragma unroll
      for (int mi = 0; mi < 4; ++mi) {
        const int gm = m0 + wm + mi * 16 + fg * 4;
        float s0 = 0.f, s1 = 0.f, s2 = 0.f, s3 = 0.f;
#pragma unroll
        for (int ni = 0; ni < 4; ++ni) {
          const int col = (wavecol + ni * 16 + fr) & 1023;
          const unsigned short u0 = f2bf(acc[mi][ni][0] * sc);
          const unsigned short u1 = f2bf(acc[mi][ni][1] * sc);
          const unsigned short u2 = f2bf(acc[mi][ni][2] * sc);
          const unsigned short u3 = f2bf(acc[mi][ni][3] * sc);
          dst[(size_t)(gm + 0) * 1024 + col] = u0;
          dst[(size_t)(gm + 1) * 1024 + col] = u1;
          dst[(size_t)(gm + 2) * 1024 + col] = u2;
          dst[(size_t)(gm + 3) * 1024 + col] = u3;
          const float r0 = bf2f(u0), r1 = bf2f(u1), r2 = bf2f(u2), r3 = bf2f(u3);
          s0 += r0 * r0; s1 += r1 * r1; s2 += r2 * r2; s3 += r3 * r3;
        }
#pragma unroll
        for (int off2 = 1; off2 < 16; off2 <<= 1) {    // reduce over fr lanes
          s0 += __shfl_xor(s0, off2);
          s1 += __shfl_xor(s1, off2);
          s2 += __shfl_xor(s2, off2);
          s3 += __shfl_xor(s3, off2);
        }
        if (fr == 0) {
          const int bb = gm >> 11;
          float4 o4;
          o4.x = s0 * qscale; o4.y = s1 * qscale;
          o4.z = s2 * qscale; o4.w = s3 * qscale;
          *(float4*)(dq + (bb * 16 + hh) * 2048 + (gm & 2047)) = o4;
        }
      }
    } else {                                           // V -> Vt[bh][d][n]
#pragma unroll
      for (int mi = 0; mi < 4; ++mi) {
        const int gm = m0 + wm + mi * 16 + fg * 4;
#pragma unroll
        for (int ni = 0; ni < 4; ++ni) {
          const int gn = n0 + wn + ni * 16 + fr;
          const int col = gn & 1023;
          ushort4 o4;
          o4.x = f2bf(acc[mi][ni][0]); o4.y = f2bf(acc[mi][ni][1]);
          o4.z = f2bf(acc[mi][ni][2]); o4.w = f2bf(acc[mi][ni][3]);
          const int bb = gm >> 11, nn = gm & 2047;
          const int hh = col >> 6, dd = col & 63;
          unsigned short* vt = outw + (size_t)2 * 4194304u;
          *(ushort4*)(vt + ((size_t)((bb * 16 + hh) * 64 + dd)) * 2048 + nn) = o4;
        }
      }
    }
  }
}

// ---------------- prep: maskf / FullVm / kmax / den_base ----------------
// grid 256 = bh*8 + kchunk. Reads Vt, mask, ksqp (complete: gemm preceded).
__global__ __launch_bounds__(256)
void prep_kernel(const unsigned short* __restrict__ Vt,
                 const int* __restrict__ mask,
                 const float* __restrict__ ksqp,
                 float* __restrict__ maskf,
                 float* __restrict__ FullVm,
                 float* __restrict__ den_base,
                 unsigned* __restrict__ kmax_bits) {
  const int bh = blockIdx.x >> 3, c = blockIdx.x & 7;
  const int b = bh >> 4;
  const int wave = threadIdx.x >> 6, lane = threadIdx.x & 63;
  const int k0 = c * 256;
  const int4 mi4 = *(const int4*)(mask + b * 2048 + k0 + lane * 4);
  const float mvx = mi4.x ? 1.f : 0.f, mvy = mi4.y ? 1.f : 0.f;
  const float mvz = mi4.z ? 1.f : 0.f, mvw = mi4.w ? 1.f : 0.f;
  // FullVm[bh][d] += sum_{k in chunk} m[k]*V[k][d]
#pragma unroll 4
  for (int dr = wave * 16; dr < wave * 16 + 16; ++dr) {
    const ushort4 v = *(const ushort4*)(Vt + ((size_t)bh * 64 + dr) * 2048 + k0 + lane * 4);
    float s = bf2f(v.x) * mvx + bf2f(v.y) * mvy + bf2f(v.z) * mvz + bf2f(v.w) * mvw;
#pragma unroll
    for (int off = 32; off >= 1; off >>= 1) s += __shfl_xor(s, off);
    if (lane == 0) atomicAdd(&FullVm[bh * 64 + dr], s);
  }
  if (wave == 0) {   // kmax over this ksqp chunk (vals <= 0: fmax == uint-min)
    const float4 kq = *(const float4*)(ksqp + bh * 2048 + k0 + lane * 4);
    float mx = fmaxf(fmaxf(kq.x, kq.y), fmaxf(kq.z, kq.w));
#pragma unroll
    for (int off = 32; off >= 1; off >>= 1) mx = fmaxf(mx, __shfl_xor(mx, off));
    if (lane == 0) atomicMin(&kmax_bits[bh], __float_as_uint(mx));
  }
  if (wave == 1 && (bh & 15) == 0) {   // maskf
    float4 mf; mf.x = mvx; mf.y = mvy; mf.z = mvz; mf.w = mvw;
    *(float4*)(maskf + b * 2048 + k0 + lane * 4) = mf;
  }
  if (wave == 2 && (bh & 15) == 0) {   // den_base[b] += sum m over chunk
    float s = mvx + mvy + mvz + mvw;
#pragma unroll
    for (int off = 32; off >= 1; off >>= 1) s += __shfl_xor(s, off);
    if (lane == 0) atomicAdd(&den_base[b], s);
  }
}

// ---------------- fused RBF attention, classify-and-skip (2-wave blocks) ----------------
// grid (32 bh, 32 qtiles), 2 waves; wave = q-group (32 rows), full 64-k tile
// per wave as two sequential 32-k sets (st regs reused). Ring-4 + vmcnt(8):
// two K-tiles in flight. den complete per wave -> no end-combine.
__global__ __launch_bounds__(128)
void attn_kernel(const unsigned short* __restrict__ Qbf,
                 const unsigned short* __restrict__ Kbf,
                 const unsigned short* __restrict__ Vt,
                 const float* __restrict__ qsqp,
                 const float* __restrict__ ksqp,
                 const float* __restrict__ maskf,
                 const float* __restrict__ FullVm,
                 const float* __restrict__ den_base,
                 const float* __restrict__ kmaxb,
                 unsigned short* __restrict__ Obf) {
  __shared__ unsigned short Ks[4][4096];   // [buf][64 k][64 d] swizzled (chunk^=row&7)

  const int bh = blockIdx.x;
  const int b = bh >> 4, h = bh & 15;
  const int t = threadIdx.x;
  const int wave = t >> 6, lane = t & 63;
  const int li = lane & 31, hi = lane >> 5;
  const int q0 = blockIdx.y * 64 + wave * 32;
  const int qrow = q0 + li;

  // Q fragments: B-operand, lane holds Q[qrow][dblk*16 + hi*8 + e]
  const unsigned short* Qr = Qbf + (size_t)(b * 2048 + qrow) * 1024 + h * 64 + hi * 8;
  bf16x8 qf[4];
#pragma unroll
  for (int dblk = 0; dblk < 4; ++dblk) qf[dblk] = *(const bf16x8*)(Qr + dblk * 16);

  const float qsl = qsqp[bh * 2048 + qrow];
  const float thr = -14.0f - qsl - kmaxb[bh];   // st_raw > thr possible => slow path

  const unsigned short* Kbase = Kbf + (size_t)b * 2048 * 1024 + h * 64;
  const unsigned short* VtB = Vt + (size_t)bh * 64 * 2048;

  // staging: 8KB tile = 512 x 16B chunks; 128 threads own 4 chunks each.
  // row = p>>3, slot cp = p&7 holds logical chunk cl = cp ^ (row&7).
  const int p0 = t,        r0 = p0 >> 3, c0 = (p0 & 7) ^ (r0 & 7);
  const int p1 = 128 + t,  r1 = p1 >> 3, c1 = (p1 & 7) ^ (r1 & 7);
  const int p2 = 256 + t,  r2 = p2 >> 3, c2 = (p2 & 7) ^ (r2 & 7);
  const int p3 = 384 + t,  r3 = p3 >> 3, c3 = (p3 & 7) ^ (r3 & 7);

  f32x16 oa0, oa1;
#pragma unroll
  for (int r = 0; r < 16; ++r) { oa0[r] = 0.f; oa1[r] = 0.f; }
  float den = 0.f;

#define STAGE(bi, tj)                                                                               \
  do {                                                                                              \
    const int j0s = (tj) * 64;                                                                      \
    __builtin_amdgcn_global_load_lds((gas_t)(const void*)(Kbase + (size_t)(j0s + r0) * 1024 + c0 * 8), \
                                     (las_t)(void*)(Ks[bi] + p0 * 8), 16, 0, 0);                    \
    __builtin_amdgcn_global_load_lds((gas_t)(const void*)(Kbase + (size_t)(j0s + r1) * 1024 + c1 * 8), \
                                     (las_t)(void*)(Ks[bi] + p1 * 8), 16, 0, 0);                    \
    __builtin_amdgcn_global_load_lds((gas_t)(const void*)(Kbase + (size_t)(j0s + r2) * 1024 + c2 * 8), \
                                     (las_t)(void*)(Ks[bi] + p2 * 8), 16, 0, 0);                    \
    __builtin_amdgcn_global_load_lds((gas_t)(const void*)(Kbase + (size_t)(j0s + r3) * 1024 + c3 * 8), \
                                     (las_t)(void*)(Ks[bi] + p3 * 8), 16, 0, 0);                    \
  } while (0)

  STAGE(0, 0);
  STAGE(1, 1);
  STAGE(2, 2);

  const int ksw = li & 7;            // K LDS row = s*32+li; s*32 ≡ 0 (mod 8)

  for (int tj = 0; tj < 32; ++tj) {
    const int cur = tj & 3;
    if (tj + 2 < 32) SYNC_VM(8);
    else if (tj + 1 < 32) SYNC_VM(4);
    else SYNC_VM(0);
    if (tj + 3 < 32) STAGE((tj + 3) & 3, tj + 3);

#pragma unroll
    for (int s = 0; s < 2; ++s) {    // two 32-k sets of the 64-k tile
      // QK^T raw: st = K_rows(s*32..s*32+31) * Q^T (C-init 0)
      const unsigned short* Krow = Ks[cur] + (s * 32 + li) * 64;
      f32x16 st;
#pragma unroll
      for (int r = 0; r < 16; ++r) st[r] = 0.f;
#pragma unroll
      for (int dblk = 0; dblk < 4; ++dblk) {
        const bf16x8 kf = *(const bf16x8*)(Krow + ((dblk * 2 + hi) ^ ksw) * 8);
        st = __builtin_amdgcn_mfma_f32_32x32x16_bf16(kf, qf[dblk], st, 0, 0, 0);
      }

      // max tree
      const float a0 = fmaxf(fmaxf(st[0], st[1]), st[2]);
      const float a1 = fmaxf(fmaxf(st[3], st[4]), st[5]);
      const float a2 = fmaxf(fmaxf(st[6], st[7]), st[8]);
      const float a3 = fmaxf(fmaxf(st[9], st[10]), st[11]);
      const float a4 = fmaxf(fmaxf(st[12], st[13]), st[14]);
      const float a5 = fmaxf(fmaxf(a0, a1), st[15]);
      const float a6 = fmaxf(fmaxf(a2, a3), a4);
      const float lmax = fmaxf(a5, a6);

      if (__any(lmax > thr)) {
        // ---- slow path (rare): ds = m * expm1(2^z), z = st + qsl + ksq' ----
        const int j0 = tj * 64 + s * 32;
        const float* ksb2 = ksqp + bh * 2048 + j0 + 4 * hi;
        const float* mfb2 = maskf + b * 2048 + j0 + 4 * hi;
        const float4 kq0 = *(const float4*)(ksb2);
        const float4 kq1 = *(const float4*)(ksb2 + 8);
        const float4 kq2 = *(const float4*)(ksb2 + 16);
        const float4 kq3 = *(const float4*)(ksb2 + 24);
        const float4 mf0 = *(const float4*)(mfb2);
        const float4 mf1 = *(const float4*)(mfb2 + 8);
        const float4 mf2 = *(const float4*)(mfb2 + 16);
        const float4 mf3 = *(const float4*)(mfb2 + 24);
        const float kqa[16] = {kq0.x, kq0.y, kq0.z, kq0.w, kq1.x, kq1.y, kq1.z, kq1.w,
                               kq2.x, kq2.y, kq2.z, kq2.w, kq3.x, kq3.y, kq3.z, kq3.w};
        const float mfa[16] = {mf0.x, mf0.y, mf0.z, mf0.w, mf1.x, mf1.y, mf1.z, mf1.w,
                               mf2.x, mf2.y, mf2.z, mf2.w, mf3.x, mf3.y, mf3.z, mf3.w};
        float dsv[16];
#pragma unroll
        for (int r = 0; r < 16; ++r) {
          const float z = __builtin_fminf(st[r] + qsl + kqa[r], 0.f);
          const float sx = EXP2(z);
          // expm1(s)/s = 1 + s/2 + s^2/6 + s^3/24 + s^4/120
          float pl = __builtin_fmaf(sx, 1.f / 120.f, 1.f / 24.f);
          pl = __builtin_fmaf(sx, pl, 1.f / 6.f);
          pl = __builtin_fmaf(sx, pl, 0.5f);
          pl = __builtin_fmaf(sx, pl, 1.f);
          const float d_ = sx * pl * mfa[r];
          dsv[r] = d_;
          den += d_;
        }

        // P redistribution: cvt_pk pairs, permlane32_swap -> B-fragments
        unsigned u00 = cvt_pk_bf16(dsv[0],  dsv[1]);
        unsigned u01 = cvt_pk_bf16(dsv[2],  dsv[3]);
        unsigned u10 = cvt_pk_bf16(dsv[4],  dsv[5]);
        unsigned u11 = cvt_pk_bf16(dsv[6],  dsv[7]);
        unsigned u20 = cvt_pk_bf16(dsv[8],  dsv[9]);
        unsigned u21 = cvt_pk_bf16(dsv[10], dsv[11]);
        unsigned u30 = cvt_pk_bf16(dsv[12], dsv[13]);
        unsigned u31 = cvt_pk_bf16(dsv[14], dsv[15]);
        permlane32_swap(u00, u10);
        permlane32_swap(u01, u11);
        permlane32_swap(u20, u30);
        permlane32_swap(u21, u31);
        union { unsigned u[4]; bf16x8 v; } pf0, pf1;
        pf0.u[0] = u00; pf0.u[1] = u01; pf0.u[2] = u10; pf0.u[3] = u11;
        pf1.u[0] = u20; pf1.u[1] = u21; pf1.u[2] = u30; pf1.u[3] = u31;

        // PV: O^T[d][q] += V^T[d][k] * dP[k][q];  V direct from global (L2-hit)
#pragma unroll
        for (int dh = 0; dh < 2; ++dh) {
          const unsigned short* Vrow = VtB + (size_t)(dh * 32 + li) * 2048 + j0;
          const bf16x8 vf0 = *(const bf16x8*)(Vrow + hi * 8);
          const bf16x8 vf1 = *(const bf16x8*)(Vrow + 16 + hi * 8);
          if (dh == 0) {
            oa0 = __builtin_amdgcn_mfma_f32_32x32x16_bf16(vf0, pf0.v, oa0, 0, 0, 0);
            oa0 = __builtin_amdgcn_mfma_f32_32x32x16_bf16(vf1, pf1.v, oa0, 0, 0, 0);
          } else {
            oa1 = __builtin_amdgcn_mfma_f32_32x32x16_bf16(vf0, pf0.v, oa1, 0, 0, 0);
            oa1 = __builtin_amdgcn_mfma_f32_32x32x16_bf16(vf1, pf1.v, oa1, 0, 0, 0);
          }
        }
      }
    }
  }
#undef STAGE

  // den over hi halves (within wave); complete per wave (wave saw all k)
  den += __shfl_xor(den, 32);
  const float inv = 1.f / (den_base[b] + den);
  const float* fvm = FullVm + bh * 64;
  unsigned short* orow = Obf + (size_t)(b * 2048 + qrow) * 1024 + h * 64;
#pragma unroll
  for (int dh = 0; dh < 2; ++dh)
#pragma unroll
    for (int w = 0; w < 4; ++w) {
      float v0, v1, v2, v3;
      if (dh == 0) {
        v0 = oa0[4 * w];     v1 = oa0[4 * w + 1];
        v2 = oa0[4 * w + 2]; v3 = oa0[4 * w + 3];
      } else {
        v0 = oa1[4 * w];     v1 = oa1[4 * w + 1];
        v2 = oa1[4 * w + 2]; v3 = oa1[4 * w + 3];
      }
      // d = 32*dh + 8*w + 4*hi + i
      const float4 fv = *(const float4*)(fvm + dh * 32 + w * 8 + hi * 4);
      ushort4 o4;
      o4.x = f2bf((v0 + fv.x) * inv);
      o4.y = f2bf((v1 + fv.y) * inv);
      o4.z = f2bf((v2 + fv.z) * inv);
      o4.w = f2bf((v3 + fv.w) * inv);
      *(ushort4*)(orow + dh * 32 + w * 8 + hi * 4) = o4;
    }
}

extern "C" void kernel_launch(void* const* d_in, const int* in_sizes, int n_in,
                              void* d_out, int out_size, void* d_ws, size_t ws_size,
                              hipStream_t stream) {
  const float* x  = (const float*)d_in[0];
  const float* Wq = (const float*)d_in[1];
  const float* Wk = (const float*)d_in[2];
  const float* Wv = (const float*)d_in[3];
  const float* Wo = (const float*)d_in[4];
  const int* mask = (const int*)d_in[5];

  unsigned short* ws = (unsigned short*)d_ws;
  const size_t SZ = 4194304;                 // 4096*1024
  unsigned short* xbf = ws;
  unsigned short* Wbf = ws + SZ;             // Wq,Wk,Wv,Wo @ +0/+1M/+2M/+3M
  unsigned short* Qbf = ws + 2 * SZ;
  unsigned short* Kbf = ws + 3 * SZ;         // must be Qbf + SZ (gemm mode 0 relies on it)
  unsigned short* Vt  = ws + 4 * SZ;         // [bh][64][2048]
  unsigned short* Obf = ws + 5 * SZ;
  float* qsqp = (float*)(ws + 6 * SZ);
  float* ksqp = qsqp + 65536;
  float* maskf = ksqp + 65536;
  float* FullVm = maskf + 4096;
  float* den_base = FullVm + 2048;
  float* kmaxb = den_base + 2;               // also used as unsigned bits

  // 1) f32 -> bf16 (single fused launch; also inits atomic targets)
  cvt_all<<<8192, 256, 0, stream>>>(x, Wq, Wk, Wv, Wo, xbf, Wbf,
                                    FullVm, den_base, (unsigned*)kmaxb);

  // 2) fused QKV projection: x @ [Wq;Wk;Wv]^T (Q prescaled; emits qsqp/ksqp)
  gemm_bt<0><<<dim3(32, 24), 256, 0, stream>>>(xbf, Wbf, Qbf, 1024, qsqp, ksqp);

  // 3) prep: maskf / FullVm / kmax(from ksqp) / den_base
  prep_kernel<<<256, 256, 0, stream>>>(Vt, mask, ksqp, maskf, FullVm, den_base,
                                       (unsigned*)kmaxb);

  // 4) fused RBF attention -> Obf
  attn_kernel<<<dim3(32, 32), 128, 0, stream>>>(Qbf, Kbf, Vt, qsqp, ksqp, maskf,
                                                FullVm, den_base, kmaxb, Obf);

  // 5) output projection: Obf @ Wo^T -> f32 d_out (deep-pipelined: 1 block/CU)
  gemm_bt<1><<<dim3(32, 8), 256, 0, stream>>>(Obf, Wbf + 3145728, d_out, 1024,
                                              nullptr, nullptr);
}